// Round 1
// baseline (451.642 us; speedup 1.0000x reference)
//
#include <hip/hip_runtime.h>
#include <math.h>

#define T_LEN   8000
#define NT4     (T_LEN / 256)          // 31 full float4 tiles = 7936 elems
#define TAILOFF (NT4 * 256)            // 7936; tail = 64 scalar elems
#define FLOORV  1e-6f

// Fast-path PCEN pointwise (identical numerics to the verified 437.8us kernel):
//   x/(f+ema)^a = x * exp2(-a*log2(f+ema)); (.)^r = exp2(r*log2(.))
__device__ __forceinline__ float pcen_pt(float xv, float em,
                                         float na, float d, float r, float dr)
{
    float u  = __builtin_amdgcn_exp2f(na * __builtin_amdgcn_logf(FLOORV + em));
    float b2 = fmaf(xv, u, d);          // x*u + d  (> 0)
    return __builtin_amdgcn_exp2f(r * __builtin_amdgcn_logf(b2)) - dr;
}

// One WAVE per (b,c) row. No LDS, no __syncthreads.
// EMA recurrence ema[t] = w*x[t] + q*ema[t-1] handled as an affine-map scan:
//  - lane-local compose over 4 contiguous elems (float4, coalesced)
//  - 6-step __shfl_up inclusive scan of (A,D) affine pairs across 64 lanes
//  - cross-tile carry = single dependent fma (serial chain ~31 fma per row)
__global__ __launch_bounds__(256, 8) void pcen_kernel(
    const float* __restrict__ x,
    const float* __restrict__ alpha,
    const float* __restrict__ delta,
    const float* __restrict__ root,
    const float* __restrict__ emaw,
    float* __restrict__ out,
    int C, int rows)
{
    const int wave = threadIdx.x >> 6;
    const int lane = threadIdx.x & 63;
    const int row  = blockIdx.x * 4 + wave;
    if (row >= rows) return;
    const int c = row % C;

    const float a  = fminf(alpha[c], 1.0f);
    const float d  = delta[c];
    const float rt = fmaxf(root[c], 1.0f);
    const float r  = 1.0f / rt;
    const float w  = fminf(fmaxf(emaw[c], 0.0f), 1.0f);
    const float q  = 1.0f - w;
    const float na = -a;
    const float dr = __builtin_amdgcn_exp2f(r * __builtin_amdgcn_logf(d));
    const float q2 = q * q, q4 = q2 * q2;

    const float*  xr  = x   + (size_t)row * T_LEN;
    float*        orw = out + (size_t)row * T_LEN;
    const float4* xv4 = (const float4*)xr;
    float4*       ov4 = (float4*)orw;

    // ema init: reference scan gives ema[0] = x[0] exactly; carry-in e = x[0]
    // makes element 0 produce w*x0 + q*x0 = x0. Broadcast load (same addr).
    float e = xr[0];

    float4 v = xv4[lane];                       // prefetch tile 0
    for (int t = 0; t < NT4; ++t) {
        float4 cur = v;
        if (t + 1 < NT4) v = xv4[(t + 1) * 64 + lane];   // prefetch next tile

        // lane-local affine map over its 4 elems: e_out = A + D*e_in
        float A = w * cur.x;
        A = fmaf(q, A, w * cur.y);
        A = fmaf(q, A, w * cur.z);
        A = fmaf(q, A, w * cur.w);
        float D = q4;

        // inclusive affine-map scan across lanes (lower lane = earlier t)
        #pragma unroll
        for (int off = 1; off < 64; off <<= 1) {
            float Alo = __shfl_up(A, off);
            float Dlo = __shfl_up(D, off);
            if (lane >= off) { A = fmaf(D, Alo, A); D *= Dlo; }
        }

        // carry-in for this lane = exclusive map applied to tile carry e
        float Aex = __shfl_up(A, 1);
        float Dex = __shfl_up(D, 1);
        float ein = (lane == 0) ? e : fmaf(Dex, e, Aex);

        // tile carry-out (whole-tile map from lane 63) — the only serial dep
        float A63 = __shfl(A, 63);
        float D63 = __shfl(D, 63);
        float enext = fmaf(D63, e, A63);

        // replay 4 elems with exact carry-in + pointwise PCEN
        float e0 = fmaf(q, ein, w * cur.x);
        float e1 = fmaf(q, e0,  w * cur.y);
        float e2 = fmaf(q, e1,  w * cur.z);
        float e3 = fmaf(q, e2,  w * cur.w);
        float4 o;
        o.x = pcen_pt(cur.x, e0, na, d, r, dr);
        o.y = pcen_pt(cur.y, e1, na, d, r, dr);
        o.z = pcen_pt(cur.z, e2, na, d, r, dr);
        o.w = pcen_pt(cur.w, e3, na, d, r, dr);
        ov4[t * 64 + lane] = o;

        e = enext;
    }

    // tail: 64 scalar elements (7936..7999)
    {
        float xt = xr[TAILOFF + lane];
        float A = w * xt;
        float D = q;
        #pragma unroll
        for (int off = 1; off < 64; off <<= 1) {
            float Alo = __shfl_up(A, off);
            float Dlo = __shfl_up(D, off);
            if (lane >= off) { A = fmaf(D, Alo, A); D *= Dlo; }
        }
        float em = fmaf(D, e, A);               // inclusive map applied to carry
        orw[TAILOFF + lane] = pcen_pt(xt, em, na, d, r, dr);
    }
}

extern "C" void kernel_launch(void* const* d_in, const int* in_sizes, int n_in,
                              void* d_out, int out_size, void* d_ws, size_t ws_size,
                              hipStream_t stream) {
    const float* x     = (const float*)d_in[0];
    const float* alpha = (const float*)d_in[1];
    const float* delta = (const float*)d_in[2];
    const float* root  = (const float*)d_in[3];
    const float* emaw  = (const float*)d_in[4];
    float* out = (float*)d_out;

    const int C    = in_sizes[1];              // 64
    const int rows = in_sizes[0] / T_LEN;      // B*C = 8192

    const int blocks = (rows + 3) / 4;         // 4 rows (waves) per block
    pcen_kernel<<<blocks, 256, 0, stream>>>(x, alpha, delta, root, emaw, out, C, rows);
}

// Round 2
// 447.435 us; speedup vs baseline: 1.0094x; 1.0094x over previous
//
#include <hip/hip_runtime.h>
#include <math.h>

#define T_LEN   8000
#define NT4     (T_LEN / 256)          // 31 full float4 tiles = 7936 elems
#define TAILOFF (NT4 * 256)            // 7936; tail = 64 scalar elems
#define FLOORV  1e-6f

// Fast-path PCEN pointwise (identical numerics to the verified kernel):
//   x/(f+ema)^a = x * exp2(-a*log2(f+ema)); (.)^r = exp2(r*log2(.))
__device__ __forceinline__ float pcen_pt(float xv, float em,
                                         float na, float d, float r, float dr)
{
    float u  = __builtin_amdgcn_exp2f(na * __builtin_amdgcn_logf(FLOORV + em));
    float b2 = fmaf(xv, u, d);          // x*u + d  (> 0)
    return __builtin_amdgcn_exp2f(r * __builtin_amdgcn_logf(b2)) - dr;
}

// One WAVE per (b,c) row. No LDS, no __syncthreads.
// EMA recurrence ema[t] = w*x[t] + q*ema[t-1] as an affine-map scan.
// Key fact vs R1: the decay part of every lane's local map is the SAME
// (q^4), so the Hillis-Steele multiplier at step s is the wave-uniform
// constant (q^4)^(2^s) and the exclusive decay is q^(4*lane) — no D
// component needs to be scanned or shuffled. 6 shfl + 6 fma per tile.
__global__ __launch_bounds__(256, 8) void pcen_kernel(
    const float* __restrict__ x,
    const float* __restrict__ alpha,
    const float* __restrict__ delta,
    const float* __restrict__ root,
    const float* __restrict__ emaw,
    float* __restrict__ out,
    int C, int rows)
{
    const int wave = threadIdx.x >> 6;
    const int lane = threadIdx.x & 63;
    const int row  = blockIdx.x * 4 + wave;
    if (row >= rows) return;
    const int c = row % C;

    const float a  = fminf(alpha[c], 1.0f);
    const float d  = delta[c];
    const float rt = fmaxf(root[c], 1.0f);
    const float r  = 1.0f / rt;
    const float w  = fminf(fmaxf(emaw[c], 0.0f), 1.0f);
    const float q  = 1.0f - w;
    const float na = -a;
    const float dr = __builtin_amdgcn_exp2f(r * __builtin_amdgcn_logf(d));

    // scan constants: c_s = (q^4)^(2^s); q256 = q^256 is the tile carry decay
    const float q2 = q * q, q4 = q2 * q2;
    const float c0 = q4, c1 = c0 * c0, c2 = c1 * c1,
                c3 = c2 * c2, c4 = c3 * c3, c5 = c4 * c4;
    const float q256 = c5 * c5;
    // per-lane exclusive decay q^(4*lane) via lane-bit chain (exact, no log)
    float qpow = 1.0f;
    qpow *= (lane & 1 ) ? c0 : 1.0f;
    qpow *= (lane & 2 ) ? c1 : 1.0f;
    qpow *= (lane & 4 ) ? c2 : 1.0f;
    qpow *= (lane & 8 ) ? c3 : 1.0f;
    qpow *= (lane & 16) ? c4 : 1.0f;
    qpow *= (lane & 32) ? c5 : 1.0f;

    const float*  xr  = x   + (size_t)row * T_LEN;
    float*        orw = out + (size_t)row * T_LEN;
    const float4* xv4 = (const float4*)xr;
    float4*       ov4 = (float4*)orw;

    // ema init: carry-in e = x[0] makes element 0 produce x[0] (ref semantics)
    float e = xr[0];

    // 2-deep prefetch: two 1 KB tiles in flight per wave
    float4 va = xv4[lane];
    float4 vb = xv4[64 + lane];

    for (int t = 0; t < NT4; ++t) {
        float4 cur = va;
        va = vb;
        const int pf = (t + 2 < NT4) ? (t + 2) : (NT4 - 1);
        vb = xv4[pf * 64 + lane];

        // lane-local affine numerator over its 4 elems
        float A = w * cur.x;
        A = fmaf(q, A, w * cur.y);
        A = fmaf(q, A, w * cur.z);
        A = fmaf(q, A, w * cur.w);

        // inclusive scan of A with uniform decay constants
        float s0 = __shfl_up(A, 1);  if (lane >= 1 ) A = fmaf(c0, s0, A);
        float s1 = __shfl_up(A, 2);  if (lane >= 2 ) A = fmaf(c1, s1, A);
        float s2 = __shfl_up(A, 4);  if (lane >= 4 ) A = fmaf(c2, s2, A);
        float s3 = __shfl_up(A, 8);  if (lane >= 8 ) A = fmaf(c3, s3, A);
        float s4 = __shfl_up(A, 16); if (lane >= 16) A = fmaf(c4, s4, A);
        float s5 = __shfl_up(A, 32); if (lane >= 32) A = fmaf(c5, s5, A);

        // carry-in for this lane: ein = q^(4*lane)*e + A[lane-1]
        float Aex = __shfl_up(A, 1);
        Aex = (lane == 0) ? 0.0f : Aex;
        float ein = fmaf(qpow, e, Aex);

        // tile carry-out (only serial dependence): e' = q^256*e + A[63]
        float A63 = __shfl(A, 63);
        float enext = fmaf(q256, e, A63);

        // replay 4 elems with exact carry-in + pointwise PCEN
        float e0 = fmaf(q, ein, w * cur.x);
        float e1 = fmaf(q, e0,  w * cur.y);
        float e2 = fmaf(q, e1,  w * cur.z);
        float e3 = fmaf(q, e2,  w * cur.w);
        float4 o;
        o.x = pcen_pt(cur.x, e0, na, d, r, dr);
        o.y = pcen_pt(cur.y, e1, na, d, r, dr);
        o.z = pcen_pt(cur.z, e2, na, d, r, dr);
        o.w = pcen_pt(cur.w, e3, na, d, r, dr);
        ov4[t * 64 + lane] = o;

        e = enext;
    }

    // tail: 64 scalar elements (7936..7999), local decay q per lane
    {
        float xt = xr[TAILOFF + lane];
        float A  = w * xt;
        const float d0 = q, d1 = d0 * d0, d2 = d1 * d1,
                    d3 = d2 * d2, d4 = d3 * d3, d5 = d4 * d4;
        float s0 = __shfl_up(A, 1);  if (lane >= 1 ) A = fmaf(d0, s0, A);
        float s1 = __shfl_up(A, 2);  if (lane >= 2 ) A = fmaf(d1, s1, A);
        float s2 = __shfl_up(A, 4);  if (lane >= 4 ) A = fmaf(d2, s2, A);
        float s3 = __shfl_up(A, 8);  if (lane >= 8 ) A = fmaf(d3, s3, A);
        float s4 = __shfl_up(A, 16); if (lane >= 16) A = fmaf(d4, s4, A);
        float s5 = __shfl_up(A, 32); if (lane >= 32) A = fmaf(d5, s5, A);
        // inclusive decay q^(lane+1) applied to carry e
        float qpl = 1.0f;
        qpl *= (lane & 1 ) ? d0 : 1.0f;
        qpl *= (lane & 2 ) ? d1 : 1.0f;
        qpl *= (lane & 4 ) ? d2 : 1.0f;
        qpl *= (lane & 8 ) ? d3 : 1.0f;
        qpl *= (lane & 16) ? d4 : 1.0f;
        qpl *= (lane & 32) ? d5 : 1.0f;
        float em = fmaf(q * qpl, e, A);
        orw[TAILOFF + lane] = pcen_pt(xt, em, na, d, r, dr);
    }
}

extern "C" void kernel_launch(void* const* d_in, const int* in_sizes, int n_in,
                              void* d_out, int out_size, void* d_ws, size_t ws_size,
                              hipStream_t stream) {
    const float* x     = (const float*)d_in[0];
    const float* alpha = (const float*)d_in[1];
    const float* delta = (const float*)d_in[2];
    const float* root  = (const float*)d_in[3];
    const float* emaw  = (const float*)d_in[4];
    float* out = (float*)d_out;

    const int C    = in_sizes[1];              // 64
    const int rows = in_sizes[0] / T_LEN;      // B*C = 8192

    const int blocks = (rows + 3) / 4;         // 4 rows (waves) per block
    pcen_kernel<<<blocks, 256, 0, stream>>>(x, alpha, delta, root, emaw, out, C, rows);
}